// Round 2
// 481.928 us; speedup vs baseline: 1.1376x; 1.1376x over previous
//
#include <hip/hip_runtime.h>
#include <stdint.h>

// Problem dims (fixed by reference): B=4, S=2048, K=4096, N=4096
#define M_DIM 8192   // B*S
#define N_DIM 4096
#define K_DIM 4096
#define NKB   (K_DIM / 32)   // scale blocks along K
#define BK    64             // GEMM K-tile
#define KT    (K_DIM / BK)   // 64 K-tiles
#define ITERS (KT / 2)       // 32 main-loop iterations (2 K-tiles each)
#define GRID_WGS ((M_DIM / 256) * (N_DIM / 256))   // 32*16 = 512

typedef __bf16 bf16x8 __attribute__((ext_vector_type(8)));
typedef float  f32x4  __attribute__((ext_vector_type(4)));

// Pack two fp32 -> two bf16 in one dword: round-half-up via +0x8000, then
// v_perm_b32 grabs the high halves.
__device__ __forceinline__ uint32_t pack2_bf16(float lo, float hi) {
    union { float f; uint32_t u; } a, b;
    a.f = lo; b.f = hi;
    return __builtin_amdgcn_perm(b.u + 0x8000u, a.u + 0x8000u, 0x07060302u);
}

// ======================= PATH A: two-pass (uses d_ws) =======================

__global__ void cvt_x_kernel(const float* __restrict__ x,
                             uint32_t* __restrict__ xb, int n8) {
    int i = blockIdx.x * blockDim.x + threadIdx.x;
    if (i >= n8) return;
    const float4* p = (const float4*)x;
    float4 v0 = p[2 * i], v1 = p[2 * i + 1];
    uint4 o;
    o.x = pack2_bf16(v0.x, v0.y);
    o.y = pack2_bf16(v0.z, v0.w);
    o.z = pack2_bf16(v1.x, v1.y);
    o.w = pack2_bf16(v1.z, v1.w);
    ((uint4*)xb)[i] = o;
}

__global__ void dequant_kernel(const int* __restrict__ q,
                               const float* __restrict__ s,
                               uint32_t* __restrict__ wb, int n8) {
    int i = blockIdx.x * blockDim.x + threadIdx.x;
    if (i >= n8) return;
    int base = i << 3;                 // element index in [0, N*K)
    int n = base >> 12;                // / K_DIM
    int k = base & (K_DIM - 1);
    float sc = s[n * NKB + (k >> 5)];  // 8 elems share one 32-block
    float m8 = -8.0f * sc;
    const int4* qp = (const int4*)q;
    int4 q0 = qp[2 * i], q1 = qp[2 * i + 1];
    uint4 o;
    o.x = pack2_bf16(fmaf((float)q0.x, sc, m8), fmaf((float)q0.y, sc, m8));
    o.y = pack2_bf16(fmaf((float)q0.z, sc, m8), fmaf((float)q0.w, sc, m8));
    o.z = pack2_bf16(fmaf((float)q1.x, sc, m8), fmaf((float)q1.y, sc, m8));
    o.w = pack2_bf16(fmaf((float)q1.z, sc, m8), fmaf((float)q1.w, sc, m8));
    ((uint4*)wb)[i] = o;
}

// ============ 256x256 8-phase bf16 GEMM (m201-style template) ==============
// C = A * W^T + bias.  8 waves (2M x 4N), 512 threads, BK=64, 128 KiB LDS.
//
// LDS: lds[8][128*64] bf16 regions of 16 KB:
//   region idx = buf*4 + {0: A-mh0, 1: A-mh1, 2: B-nh0, 3: B-nh1}
//   A-region mh holds global A rows {mh*64..mh*64+63} U {128+mh*64..+63}
//   B-region nh holds global B rows {wn*64 + nh*32 .. +31 : wn=0..3}
//     stored as rw = wn*32 + rloc
// Swizzle (T2): 16B chunk c of row rw lives at slot c ^ (rw&7); staging keeps
// LDS dest linear and inverse-permutes the global source chunk (rule #21).
//
// Schedule (T3+T4): per iteration 8 phases over K-tiles {2it (buf0), 2it+1
// (buf1)}; each phase = {ds-reads, stage 1 freed 16KB region, s_barrier,
// 16 MFMA (setprio-wrapped, T5), s_barrier}. vmcnt(6) only at phases 4/8
// (3 regions = 6 loads/thread always in flight). Region staged at phase j
// was fully ds-read by all waves at a phase whose post-MFMA barrier precedes
// the stage issue, so the async DMA write never lands on live data.
//
// STAGE unit map: 0 -> A-mh0 (reg +0), 3 -> A-mh1 (reg +1),
//                 1 -> B-nh0 (reg +2), 2 -> B-nh1 (reg +3).
__global__ __launch_bounds__(512, 2)
void gemm_bf16_256_kernel(const __bf16* __restrict__ A,
                          const __bf16* __restrict__ Bw,
                          const float* __restrict__ bias,
                          float* __restrict__ C) {
    __shared__ __align__(16) __bf16 lds[8][128 * 64];   // 128 KiB

    const int t    = threadIdx.x;
    const int wave = t >> 6;
    const int lane = t & 63;
    const int wm = wave >> 2;          // 0..1
    const int wn = wave & 3;           // 0..3

    // T1: XCD-aware swizzle. 512 wgs, 8 XCDs -> 64 contiguous tiles per XCD
    // (4 bm-rows x 16 bn): A-panels L2-local per XCD, B shared via L3.
    const int flat = blockIdx.x;
    const int wgid = (flat & 7) * (GRID_WGS / 8) + (flat >> 3);
    const int bm = wgid >> 4;          // 0..31
    const int bn = wgid & 15;          // 0..15

    const __bf16* Ab = A  + (size_t)bm * 256 * K_DIM;
    const __bf16* Bb = Bw + (size_t)bn * 256 * K_DIM;

    // Staging per-thread constants. Thread t covers region-rows t>>3 and
    // (t>>3)+64 (both map to global rows gr0 and gr0+128), chunk slot t&7,
    // fetching global chunk (t&7) ^ ((t>>3)&7)  [same &7 for both rows].
    const int rr0 = t >> 3;                       // 0..63
    const int cg  = (t & 7) ^ (rr0 & 7);
    const size_t aoff = (size_t)rr0 * K_DIM + cg * 8;
    const size_t boff = (size_t)((rr0 >> 5) * 64 + (rr0 & 31)) * K_DIM + cg * 8;

#define STAGE(ktg, unit)                                                      \
    do {                                                                      \
        const __bf16* _s;                                                     \
        __bf16* _d;                                                           \
        if ((unit) == 0 || (unit) == 3) {                                     \
            const int _mh = ((unit) == 3) ? 1 : 0;                            \
            _s = Ab + (size_t)_mh * 64 * K_DIM + (size_t)(ktg) * 64 + aoff;   \
            _d = &lds[((ktg) & 1) * 4 + _mh][0] + t * 8;                      \
        } else {                                                              \
            const int _nh = ((unit) == 2) ? 1 : 0;                            \
            _s = Bb + (size_t)_nh * 32 * K_DIM + (size_t)(ktg) * 64 + boff;   \
            _d = &lds[((ktg) & 1) * 4 + 2 + _nh][0] + t * 8;                  \
        }                                                                     \
        __builtin_amdgcn_global_load_lds(                                     \
            (const __attribute__((address_space(1))) uint32_t*)_s,            \
            (__attribute__((address_space(3))) uint32_t*)_d, 16, 0, 0);       \
        __builtin_amdgcn_global_load_lds(                                     \
            (const __attribute__((address_space(1))) uint32_t*)               \
                (_s + (size_t)128 * K_DIM),                                   \
            (__attribute__((address_space(3))) uint32_t*)(_d + 4096),         \
            16, 0, 0);                                                        \
    } while (0)

    // Fragment reads: A row rw = wm*64 + i2*16 + r, B row rw = wn*32 + j2*16
    // + r; rw&7 == r&7 in both, so swizzled slot = (h*4+quad) ^ (r&7).
    const int r = lane & 15, quad = lane >> 4;
    const int s0 = quad ^ (r & 7);
    const int aRow = (wm * 64 + r) * 64;
    const int bRow = (wn * 32 + r) * 64;

    bf16x8 a[4][2], b0[2][2], b1[2][2];
    f32x4 acc[8][4] = {};

#define LOAD_A(buf, mh)                                                       \
    do { const __bf16* _p = &lds[(buf) * 4 + (mh)][aRow];                     \
        _Pragma("unroll") for (int i2 = 0; i2 < 4; ++i2) {                    \
            a[i2][0] = *(const bf16x8*)(_p + i2 * 1024 + s0 * 8);             \
            a[i2][1] = *(const bf16x8*)(_p + i2 * 1024 + (s0 ^ 4) * 8);       \
        } } while (0)

#define LOAD_B(dst, buf, nh)                                                  \
    do { const __bf16* _p = &lds[(buf) * 4 + 2 + (nh)][bRow];                 \
        _Pragma("unroll") for (int j2 = 0; j2 < 2; ++j2) {                    \
            dst[j2][0] = *(const bf16x8*)(_p + j2 * 1024 + s0 * 8);           \
            dst[j2][1] = *(const bf16x8*)(_p + j2 * 1024 + (s0 ^ 4) * 8);     \
        } } while (0)

#define MFMA16(IB, BSEL, JB)                                                  \
    do { __builtin_amdgcn_s_setprio(1);                                       \
        _Pragma("unroll") for (int i2 = 0; i2 < 4; ++i2)                      \
        _Pragma("unroll") for (int j2 = 0; j2 < 2; ++j2)                      \
        _Pragma("unroll") for (int h = 0; h < 2; ++h)                         \
            acc[(IB) + i2][(JB) + j2] =                                       \
                __builtin_amdgcn_mfma_f32_16x16x32_bf16(                      \
                    a[i2][h], BSEL[j2][h], acc[(IB) + i2][(JB) + j2],         \
                    0, 0, 0);                                                 \
        __builtin_amdgcn_s_setprio(0); } while (0)

#define BAR() do { asm volatile("" ::: "memory");                             \
                   __builtin_amdgcn_s_barrier();                              \
                   asm volatile("" ::: "memory"); } while (0)
#define VMCNT(n) asm volatile("s_waitcnt vmcnt(" #n ")" ::: "memory")

    // Prologue: stage kt0 fully + 3 regions of kt1 (7 stages = 14 loads);
    // wait until kt0 resident (vmcnt(6) -> oldest 8 loads = kt0 arrived).
    STAGE(0, 0); STAGE(0, 1); STAGE(0, 2); STAGE(0, 3);
    STAGE(1, 0); STAGE(1, 1); STAGE(1, 2);
    VMCNT(6);
    BAR();

#define KBODY(it, LAST)                                                       \
    do {                                                                      \
        const int _k0 = 2 * (it);                                             \
        /* P1 (0,0) buf0 | stage buf1.A-mh1 (kt 2it+1) */                     \
        LOAD_A(0, 0); LOAD_B(b0, 0, 0);                                       \
        STAGE(_k0 + 1, 3);                                                    \
        BAR(); MFMA16(0, b0, 0); BAR();                                       \
        /* P2 (0,1) | stage buf0.A-mh0 (kt+2); freed at P1 */                 \
        LOAD_B(b1, 0, 1);                                                     \
        if (!(LAST)) STAGE(_k0 + 2, 0);                                       \
        BAR(); MFMA16(0, b1, 2); BAR();                                       \
        /* P3 (1,1) | stage buf0.B-nh0 (unit 1); freed at P1 */               \
        LOAD_A(0, 1);                                                         \
        if (!(LAST)) STAGE(_k0 + 2, 1);                                       \
        BAR(); MFMA16(4, b1, 2); BAR();                                       \
        /* P4 (1,0) | stage buf0.B-nh1 (freed at P2); vmcnt: kt+1 resident */ \
        if (!(LAST)) STAGE(_k0 + 2, 2);                                       \
        BAR(); MFMA16(4, b0, 0);                                              \
        if (LAST) { VMCNT(0); } else { VMCNT(6); }                            \
        BAR();                                                                \
        /* P5 (0,0) buf1 | stage buf0.A-mh1 (freed at P3) */                  \
        LOAD_A(1, 0); LOAD_B(b0, 1, 0);                                       \
        if (!(LAST)) STAGE(_k0 + 2, 3);                                       \
        BAR(); MFMA16(0, b0, 0); BAR();                                       \
        /* P6 (0,1) | stage buf1.A-mh0 (kt+3; freed at P5) */                 \
        LOAD_B(b1, 1, 1);                                                     \
        if (!(LAST)) STAGE(_k0 + 3, 0);                                       \
        BAR(); MFMA16(0, b1, 2); BAR();                                       \
        /* P7 (1,1) | stage buf1.B-nh0 (freed at P5) */                       \
        LOAD_A(1, 1);                                                         \
        if (!(LAST)) STAGE(_k0 + 3, 1);                                       \
        BAR(); MFMA16(4, b1, 2); BAR();                                       \
        /* P8 (1,0) | stage buf1.B-nh1 (freed at P6); vmcnt: kt+2 resident */ \
        if (!(LAST)) STAGE(_k0 + 3, 2);                                       \
        BAR(); MFMA16(4, b0, 0);                                              \
        if (!(LAST)) { VMCNT(6); }                                            \
        BAR();                                                                \
    } while (0)

#pragma unroll 1
    for (int it = 0; it < ITERS - 1; ++it) KBODY(it, 0);
    KBODY(ITERS - 1, 1);

#undef KBODY
#undef STAGE
#undef LOAD_A
#undef LOAD_B
#undef MFMA16
#undef BAR
#undef VMCNT

    // C/D layout: col = lane&15, row = (lane>>4)*4 + reg  [m89/m91]
    const int m0 = bm * 256 + wm * 128;
    const int n0 = bn * 256 + wn * 64;
#pragma unroll
    for (int j = 0; j < 4; ++j) {
        const int col = n0 + j * 16 + r;
        const float bv = bias[col];
#pragma unroll
        for (int i = 0; i < 8; ++i) {
            const int rbase = m0 + i * 16 + quad * 4;
#pragma unroll
            for (int e = 0; e < 4; ++e)
                C[(size_t)(rbase + e) * N_DIM + col] = acc[i][j][e] + bv;
        }
    }
}

// ================= PATH B: fused, zero workspace (fallback) ================
__global__ __launch_bounds__(256)
void fused_gemm_kernel(const float* __restrict__ X,
                       const int* __restrict__ Q,
                       const float* __restrict__ S,
                       const float* __restrict__ bias,
                       float* __restrict__ C) {
    __shared__ __align__(16) __bf16 lA[128 * 32];
    __shared__ __align__(16) __bf16 lB[128 * 32];

    const int t    = threadIdx.x;
    const int wave = t >> 6;
    const int lane = t & 63;
    const int bm = blockIdx.y, bn = blockIdx.x;
    const int wm = wave >> 1, wn = wave & 1;

    const int srow = t >> 1;
    const int sc0  = (t & 1) << 4;
    const float* gX = X + (size_t)(bm * 128 + srow) * K_DIM + sc0;
    const int*   gQ = Q + (size_t)(bn * 128 + srow) * K_DIM + sc0;
    const float* gS = S + (size_t)(bn * 128 + srow) * NKB;
    __bf16* sA = lA + srow * 32 + sc0;
    __bf16* sB = lB + srow * 32 + sc0;

    const int r = lane & 15, quad = lane >> 4;
    const __bf16* fA = lA + (wm * 64 + r) * 32 + quad * 8;
    const __bf16* fB = lB + (wn * 64 + r) * 32 + quad * 8;

    f32x4 acc[4][4] = {};

    float4 x0 = ((const float4*)gX)[0];
    float4 x1 = ((const float4*)gX)[1];
    float4 x2 = ((const float4*)gX)[2];
    float4 x3 = ((const float4*)gX)[3];
    int4 q0 = ((const int4*)gQ)[0];
    int4 q1 = ((const int4*)gQ)[1];
    int4 q2 = ((const int4*)gQ)[2];
    int4 q3 = ((const int4*)gQ)[3];
    float sc = gS[0];

    for (int kt = 0; kt < NKB; ++kt) {
        uint4 pa0, pa1, pb0, pb1;
        pa0.x = pack2_bf16(x0.x, x0.y); pa0.y = pack2_bf16(x0.z, x0.w);
        pa0.z = pack2_bf16(x1.x, x1.y); pa0.w = pack2_bf16(x1.z, x1.w);
        pa1.x = pack2_bf16(x2.x, x2.y); pa1.y = pack2_bf16(x2.z, x2.w);
        pa1.z = pack2_bf16(x3.x, x3.y); pa1.w = pack2_bf16(x3.z, x3.w);
        float m8 = -8.0f * sc;
        pb0.x = pack2_bf16(fmaf((float)q0.x, sc, m8), fmaf((float)q0.y, sc, m8));
        pb0.y = pack2_bf16(fmaf((float)q0.z, sc, m8), fmaf((float)q0.w, sc, m8));
        pb0.z = pack2_bf16(fmaf((float)q1.x, sc, m8), fmaf((float)q1.y, sc, m8));
        pb0.w = pack2_bf16(fmaf((float)q1.z, sc, m8), fmaf((float)q1.w, sc, m8));
        pb1.x = pack2_bf16(fmaf((float)q2.x, sc, m8), fmaf((float)q2.y, sc, m8));
        pb1.y = pack2_bf16(fmaf((float)q2.z, sc, m8), fmaf((float)q2.w, sc, m8));
        pb1.z = pack2_bf16(fmaf((float)q3.x, sc, m8), fmaf((float)q3.y, sc, m8));
        pb1.w = pack2_bf16(fmaf((float)q3.z, sc, m8), fmaf((float)q3.w, sc, m8));

        __syncthreads();
        *(uint4*)sA = pa0; *(uint4*)(sA + 8) = pa1;
        *(uint4*)sB = pb0; *(uint4*)(sB + 8) = pb1;
        __syncthreads();

        if (kt + 1 < NKB) {
            gX += 32; gQ += 32;
            x0 = ((const float4*)gX)[0];
            x1 = ((const float4*)gX)[1];
            x2 = ((const float4*)gX)[2];
            x3 = ((const float4*)gX)[3];
            q0 = ((const int4*)gQ)[0];
            q1 = ((const int4*)gQ)[1];
            q2 = ((const int4*)gQ)[2];
            q3 = ((const int4*)gQ)[3];
            sc = gS[kt + 1];
        }

        bf16x8 af[4], bfr[4];
#pragma unroll
        for (int i = 0; i < 4; ++i)
            af[i] = *(const bf16x8*)(fA + i * 16 * 32);
#pragma unroll
        for (int j = 0; j < 4; ++j)
            bfr[j] = *(const bf16x8*)(fB + j * 16 * 32);
#pragma unroll
        for (int i = 0; i < 4; ++i)
#pragma unroll
            for (int j = 0; j < 4; ++j)
                acc[i][j] = __builtin_amdgcn_mfma_f32_16x16x32_bf16(
                    af[i], bfr[j], acc[i][j], 0, 0, 0);
    }

    const int m0 = bm * 128 + wm * 64;
    const int n0 = bn * 128 + wn * 64;
#pragma unroll
    for (int j = 0; j < 4; ++j) {
        int col = n0 + j * 16 + r;
        float bv = bias[col];
#pragma unroll
        for (int i = 0; i < 4; ++i) {
            int rbase = m0 + i * 16 + quad * 4;
#pragma unroll
            for (int e = 0; e < 4; ++e)
                C[(size_t)(rbase + e) * N_DIM + col] = acc[i][j][e] + bv;
        }
    }
}

extern "C" void kernel_launch(void* const* d_in, const int* in_sizes, int n_in,
                              void* d_out, int out_size, void* d_ws, size_t ws_size,
                              hipStream_t stream) {
    const float* x    = (const float*)d_in[0];
    const int*   qw   = (const int*)d_in[1];
    const float* sc   = (const float*)d_in[2];
    const float* bias = (const float*)d_in[3];
    float* out = (float*)d_out;

    const size_t need = ((size_t)M_DIM * K_DIM + (size_t)N_DIM * K_DIM) * 2;
    if (ws_size >= need && d_ws != nullptr) {
        uint32_t* xb = (uint32_t*)d_ws;                          // M*K bf16
        uint32_t* wb = xb + (size_t)M_DIM * K_DIM / 2;           // N*K bf16
        int n8x = M_DIM * K_DIM / 8;
        cvt_x_kernel<<<n8x / 256, 256, 0, stream>>>(x, xb, n8x);
        int n8w = N_DIM * K_DIM / 8;
        dequant_kernel<<<n8w / 256, 256, 0, stream>>>(qw, sc, wb, n8w);
        gemm_bf16_256_kernel<<<dim3(GRID_WGS), dim3(512), 0, stream>>>(
            (const __bf16*)xb, (const __bf16*)wb, bias, out);
    } else {
        dim3 grid(N_DIM / 128, M_DIM / 128);
        fused_gemm_kernel<<<grid, 256, 0, stream>>>(x, qw, sc, bias, out);
    }
}